// Round 1
// baseline (639.106 us; speedup 1.0000x reference)
//
#include <hip/hip_runtime.h>
#include <hip/hip_bf16.h>

// Problem constants (from reference): E=16 experts, C=256, CAP=4 -> F=1024, B=8, L=1024
#define EE 16
#define CC 256
#define FF 1024
#define LL 1024
#define BB 8

#define TL 128            // L-tile per workgroup
#define FC 32             // F-chunk per iteration
#define NCH (FF / FC)     // 32 chunks
#define W2STR (FC + 8)    // padded LDS row stride (bf16 elems), keeps 16B align
#define HSTR  (FC + 8)

typedef __bf16 bf16x8 __attribute__((ext_vector_type(8)));
typedef __bf16 bf16x4 __attribute__((ext_vector_type(4)));
typedef float  f32x4  __attribute__((ext_vector_type(4)));
typedef float  f32x16 __attribute__((ext_vector_type(16)));

__device__ __forceinline__ f32x4 mfma16(bf16x8 a, bf16x8 b, f32x4 c) {
    return __builtin_amdgcn_mfma_f32_16x16x32_bf16(a, b, c, 0, 0, 0);
}
__device__ __forceinline__ f32x16 mfma32(bf16x8 a, bf16x8 b, f32x16 c) {
    return __builtin_amdgcn_mfma_f32_32x32x16_bf16(a, b, c, 0, 0, 0);
}

// fp32 -> bf16 weight pre-conversion (into workspace)
__global__ void cvt_bf16_kernel(const float* __restrict__ src, __bf16* __restrict__ dst, int n4) {
    int i = blockIdx.x * blockDim.x + threadIdx.x;
    if (i >= n4) return;
    float4 v = reinterpret_cast<const float4*>(src)[i];
    bf16x4 o;
    o[0] = (__bf16)v.x; o[1] = (__bf16)v.y; o[2] = (__bf16)v.z; o[3] = (__bf16)v.w;
    reinterpret_cast<bf16x4*>(dst)[i] = o;
}

// Fused expert MLP: per block = one (b, e, l-tile of 128).
// GEMM1: h[f,l] = silu(W1[f,:]@x[:,l] + b1[f]) ; GEMM2: y[c,l] = W2[c,:]@h[:,l] + b2[c]
template <bool WBF16>
__global__ __launch_bounds__(512, 2)
void experts_kernel(const float* __restrict__ x,
                    const void* __restrict__ w1v,
                    const float* __restrict__ b1,
                    const void* __restrict__ w2v,
                    const float* __restrict__ b2,
                    float* __restrict__ out)
{
    __shared__ __align__(16) __bf16 sW2[2][CC * W2STR]; // double-buffered W2 chunk [c][f]
    __shared__ __align__(16) __bf16 sH[TL * HSTR];      // h chunk, [l][f] (B-operand layout)
    __shared__ __align__(16) float  sB1[FC];

    const int tid  = threadIdx.x;
    const int lane = tid & 63;
    const int w    = tid >> 6;          // wave 0..7
    const int l15 = lane & 15, q4 = lane >> 4;  // 16x16 frag coords
    const int l31 = lane & 31, q5 = lane >> 5;  // 32x32 frag coords

    // XCD swizzle: blockIdx%8 ~ XCD; 2 experts per XCD keeps 1MB bf16 weights L2-resident
    const int bid  = blockIdx.x;
    const int e    = ((bid & 7) << 1) | ((bid >> 3) & 1);
    const int rest = bid >> 4;
    const int bb   = rest & 7;
    const int lt   = rest >> 3;
    const int l0   = lt * TL;

    const int wf = w & 1;   // GEMM1: which 16-row f-half of the 32-chunk
    const int wl = w >> 1;  // GEMM1: which 32-col l-quarter
    const int cw = w >> 1;  // GEMM2: which 64-row c-block
    const int lw = w & 1;   // GEMM2: which 64-col l-block

    // ---- x fragments in registers: B-layout for 16x16x32 (n=l15, k=8*q4+t) ----
    bf16x8 xf[2][8];  // [l-subtile of 16][k-step of 32] = 64 VGPRs, reused all 32 chunks
    {
        const float* xbase = x + (size_t)((bb * EE + e) * CC) * LL + (l0 + 32 * wl + l15);
        #pragma unroll
        for (int li = 0; li < 2; ++li) {
            const float* xp = xbase + 16 * li;
            #pragma unroll
            for (int ks = 0; ks < 8; ++ks) {
                bf16x8 f;
                #pragma unroll
                for (int t = 0; t < 8; ++t) {
                    float v = __builtin_nontemporal_load(xp + (size_t)(32 * ks + 8 * q4 + t) * LL);
                    f[t] = (__bf16)v;
                }
                xf[li][ks] = f;
            }
        }
    }

    // ---- prologue: stage chunk 0 (W2 cols 0..31 + b1) into buffer 0 ----
    if (WBF16) {
        const __bf16* w2p = (const __bf16*)w2v + (size_t)(e * CC) * FF;
        #pragma unroll
        for (int i = 0; i < 2; ++i) {
            int s = tid + 512 * i;
            int row = s >> 2, col = (s & 3) * 8;
            uint4 v = *(const uint4*)(w2p + (size_t)row * FF + col);
            *(uint4*)(&sW2[0][row * W2STR + col]) = v;
        }
    } else {
        const float* w2p = (const float*)w2v + (size_t)(e * CC) * FF;
        #pragma unroll
        for (int i = 0; i < 4; ++i) {
            int s = tid + 512 * i;
            int row = s >> 3, col = (s & 7) * 4;
            float4 v = *(const float4*)(w2p + (size_t)row * FF + col);
            bf16x4 o;
            o[0]=(__bf16)v.x; o[1]=(__bf16)v.y; o[2]=(__bf16)v.z; o[3]=(__bf16)v.w;
            *(bf16x4*)(&sW2[0][row * W2STR + col]) = o;
        }
    }
    if (tid < FC) sB1[tid] = b1[e * FF + tid];

    // y accumulators: 2x2 tiles of 32x32 per wave = 64 VGPRs
    f32x16 accY[2][2];
    #pragma unroll
    for (int ci = 0; ci < 2; ++ci)
        #pragma unroll
        for (int li = 0; li < 2; ++li)
            #pragma unroll
            for (int r = 0; r < 16; ++r) accY[ci][li][r] = 0.0f;

    // W1 A-fragment base (read directly from global; 16KB chunk stays in L1)
    const __bf16* w1b = WBF16 ? ((const __bf16*)w1v + (size_t)(e * FF + 16 * wf + l15) * CC + 8 * q4)
                              : nullptr;
    const float*  w1f = WBF16 ? nullptr
                              : ((const float*)w1v + (size_t)(e * FF + 16 * wf + l15) * CC + 8 * q4);

    __syncthreads();

    for (int ch = 0; ch < NCH; ++ch) {
        const int fc = ch * FC;
        const int cb = ch & 1;

        // ---------- phase A: GEMM1 (h chunk) ----------
        float4 bias = *(const float4*)(&sB1[16 * wf + 4 * q4]);
        f32x4 acc1[2];
        #pragma unroll
        for (int li = 0; li < 2; ++li)
            #pragma unroll
            for (int r = 0; r < 4; ++r) acc1[li][r] = 0.0f;

        #pragma unroll
        for (int ks = 0; ks < 8; ++ks) {
            bf16x8 a;
            if (WBF16) {
                a = *(const bf16x8*)(w1b + (size_t)fc * CC + 32 * ks);
            } else {
                const float* p = w1f + (size_t)fc * CC + 32 * ks;
                float4 u0 = *(const float4*)p;
                float4 u1 = *(const float4*)(p + 4);
                a[0]=(__bf16)u0.x; a[1]=(__bf16)u0.y; a[2]=(__bf16)u0.z; a[3]=(__bf16)u0.w;
                a[4]=(__bf16)u1.x; a[5]=(__bf16)u1.y; a[6]=(__bf16)u1.z; a[7]=(__bf16)u1.w;
            }
            acc1[0] = mfma16(a, xf[0][ks], acc1[0]);
            acc1[1] = mfma16(a, xf[1][ks], acc1[1]);
        }
        // bias + SiLU + write h to LDS in [l][f] B-layout (4 consecutive f per lane)
        #pragma unroll
        for (int li = 0; li < 2; ++li) {
            bf16x4 hv;
            #pragma unroll
            for (int r = 0; r < 4; ++r) {
                float v  = acc1[li][r] + ((const float*)&bias)[r];
                float sg = v / (1.0f + __expf(-v));
                hv[r] = (__bf16)sg;
            }
            int lrow = 32 * wl + 16 * li + l15;
            *(bf16x4*)(&sH[lrow * HSTR + 16 * wf + 4 * q4]) = hv;
        }
        __syncthreads();

        // ---------- phase B: stage chunk ch+1 (loads first), GEMM2(ch), then LDS stores ----------
        const bool do_stage = (ch + 1 < NCH);
        const int fcn = fc + FC;
        const int nb  = cb ^ 1;
        uint4  stg[2];
        float4 stgf[4];
        float  breg = 0.0f;
        if (do_stage) {
            if (WBF16) {
                const __bf16* w2p = (const __bf16*)w2v + (size_t)(e * CC) * FF + fcn;
                #pragma unroll
                for (int i = 0; i < 2; ++i) {
                    int s = tid + 512 * i;
                    int row = s >> 2, col = (s & 3) * 8;
                    stg[i] = *(const uint4*)(w2p + (size_t)row * FF + col);
                }
            } else {
                const float* w2p = (const float*)w2v + (size_t)(e * CC) * FF + fcn;
                #pragma unroll
                for (int i = 0; i < 4; ++i) {
                    int s = tid + 512 * i;
                    int row = s >> 3, col = (s & 7) * 4;
                    stgf[i] = *(const float4*)(w2p + (size_t)row * FF + col);
                }
            }
            if (tid < FC) breg = b1[e * FF + fcn + tid];
        }

        #pragma unroll
        for (int ks = 0; ks < 2; ++ks) {
            bf16x8 a0  = *(const bf16x8*)(&sW2[cb][(64 * cw + l31)      * W2STR + 16 * ks + 8 * q5]);
            bf16x8 a1  = *(const bf16x8*)(&sW2[cb][(64 * cw + 32 + l31) * W2STR + 16 * ks + 8 * q5]);
            bf16x8 b0  = *(const bf16x8*)(&sH[(64 * lw + l31)      * HSTR + 16 * ks + 8 * q5]);
            bf16x8 b1v = *(const bf16x8*)(&sH[(64 * lw + 32 + l31) * HSTR + 16 * ks + 8 * q5]);
            accY[0][0] = mfma32(a0, b0,  accY[0][0]);
            accY[0][1] = mfma32(a0, b1v, accY[0][1]);
            accY[1][0] = mfma32(a1, b0,  accY[1][0]);
            accY[1][1] = mfma32(a1, b1v, accY[1][1]);
        }

        if (do_stage) {
            if (WBF16) {
                #pragma unroll
                for (int i = 0; i < 2; ++i) {
                    int s = tid + 512 * i;
                    int row = s >> 2, col = (s & 3) * 8;
                    *(uint4*)(&sW2[nb][row * W2STR + col]) = stg[i];
                }
            } else {
                #pragma unroll
                for (int i = 0; i < 4; ++i) {
                    int s = tid + 512 * i;
                    int row = s >> 3, col = (s & 7) * 4;
                    float4 v = stgf[i];
                    bf16x4 o;
                    o[0]=(__bf16)v.x; o[1]=(__bf16)v.y; o[2]=(__bf16)v.z; o[3]=(__bf16)v.w;
                    *(bf16x4*)(&sW2[nb][row * W2STR + col]) = o;
                }
            }
            if (tid < FC) sB1[tid] = breg;
        }
        __syncthreads();
    }

    // ---------- epilogue: y = acc + b2, fp32 stores ----------
    float* outp = out + (size_t)((bb * EE + e) * CC) * LL;
    const int lbase = l0 + 64 * lw;
    #pragma unroll
    for (int ci = 0; ci < 2; ++ci) {
        const int cb0 = 64 * cw + 32 * ci;
        #pragma unroll
        for (int g = 0; g < 4; ++g) {
            float4 bv = *(const float4*)(b2 + e * CC + cb0 + 8 * g + 4 * q5);
            #pragma unroll
            for (int li = 0; li < 2; ++li) {
                const int lidx = lbase + 32 * li + l31;
                #pragma unroll
                for (int r = 0; r < 4; ++r) {
                    const int c  = cb0 + 8 * g + 4 * q5 + r;  // = row (reg&3)+8*(reg>>2)+4*q5
                    float val = accY[ci][li][4 * g + r] + ((const float*)&bv)[r];
                    __builtin_nontemporal_store(val, outp + (size_t)c * LL + lidx);
                }
            }
        }
    }
}

extern "C" void kernel_launch(void* const* d_in, const int* in_sizes, int n_in,
                              void* d_out, int out_size, void* d_ws, size_t ws_size,
                              hipStream_t stream)
{
    const float* x  = (const float*)d_in[0];
    const float* W1 = (const float*)d_in[1];
    const float* b1 = (const float*)d_in[2];
    const float* W2 = (const float*)d_in[3];
    const float* b2 = (const float*)d_in[4];
    float* out = (float*)d_out;

    const size_t nW1 = (size_t)EE * FF * CC;  // 4194304
    const size_t nW2 = (size_t)EE * CC * FF;  // 4194304
    const size_t need = (nW1 + nW2) * sizeof(__bf16);  // 16.78 MB

    const dim3 grid(BB * EE * (LL / TL));  // 1024
    const dim3 block(512);

    if (ws_size >= need) {
        __bf16* w1bf = (__bf16*)d_ws;
        __bf16* w2bf = w1bf + nW1;
        int n4 = (int)(nW1 / 4);
        cvt_bf16_kernel<<<dim3((n4 + 255) / 256), dim3(256), 0, stream>>>(W1, w1bf, n4);
        n4 = (int)(nW2 / 4);
        cvt_bf16_kernel<<<dim3((n4 + 255) / 256), dim3(256), 0, stream>>>(W2, w2bf, n4);
        experts_kernel<true><<<grid, block, 0, stream>>>(x, w1bf, b1, w2bf, b2, out);
    } else {
        experts_kernel<false><<<grid, block, 0, stream>>>(x, W1, b1, W2, b2, out);
    }
}

// Round 2
// 472.480 us; speedup vs baseline: 1.3527x; 1.3527x over previous
//
#include <hip/hip_runtime.h>
#include <hip/hip_bf16.h>
#include <stdint.h>

// E=16 experts, C=256, CAP=4 -> F=1024, B=8, L=1024
#define EE 16
#define CC 256
#define FF 1024
#define LL 1024
#define BB 8
#define TL 128            // L-tile per block
#define FC 32             // f-chunk
#define NCH 32            // FF/FC
#define HSTR 56           // h row stride (bf16): 112 B, 16B-aligned for b128

typedef __bf16 bf16x8 __attribute__((ext_vector_type(8)));
typedef __bf16 bf16x4 __attribute__((ext_vector_type(4)));
typedef float  f32x4  __attribute__((ext_vector_type(4)));

__device__ __forceinline__ f32x4 mfma16(bf16x8 a, bf16x8 b, f32x4 c) {
    return __builtin_amdgcn_mfma_f32_16x16x32_bf16(a, b, c, 0, 0, 0);
}

// async global->LDS, 16B per lane; lds dest = wave-uniform base + lane*16
__device__ __forceinline__ void gld_lds16(const __bf16* g, __bf16* l) {
    __builtin_amdgcn_global_load_lds(
        (const __attribute__((address_space(1))) void*)g,
        (__attribute__((address_space(3))) void*)l, 16, 0, 0);
}

// ---- weight pre-permute kernels (fp32 -> bf16, granule-transposed) ----
// W1ws[(((e*32+ch)*32+cg)*32+f)*8+j] = W1[(e*1024+ch*32+f)*256 + cg*8 + j]
__global__ void cvt_w1(const float* __restrict__ W1, __bf16* __restrict__ ws) {
    int g = blockIdx.x * blockDim.x + threadIdx.x;   // 524288 granules
    int f  = g & 31;
    int cg = (g >> 5) & 31;
    int ec = g >> 10;
    int ch = ec & 31, e = ec >> 5;
    const float* s = W1 + ((size_t)(e * 1024 + ch * 32 + f)) * 256 + cg * 8;
    float4 v0 = *(const float4*)s;
    float4 v1 = *(const float4*)(s + 4);
    bf16x8 o;
    o[0]=(__bf16)v0.x; o[1]=(__bf16)v0.y; o[2]=(__bf16)v0.z; o[3]=(__bf16)v0.w;
    o[4]=(__bf16)v1.x; o[5]=(__bf16)v1.y; o[6]=(__bf16)v1.z; o[7]=(__bf16)v1.w;
    *(bf16x8*)(ws + (size_t)g * 8) = o;
}
// W2ws[(((e*32+ch)*4+fg)*256+c)*8+j] = W2[(e*256+c)*1024 + ch*32 + fg*8 + j]
__global__ void cvt_w2(const float* __restrict__ W2, __bf16* __restrict__ ws) {
    int g = blockIdx.x * blockDim.x + threadIdx.x;   // 524288 granules
    int c  = g & 255;
    int fg = (g >> 8) & 3;
    int ec = g >> 10;
    int ch = ec & 31, e = ec >> 5;
    const float* s = W2 + ((size_t)(e * 256 + c)) * 1024 + ch * 32 + fg * 8;
    float4 v0 = *(const float4*)s;
    float4 v1 = *(const float4*)(s + 4);
    bf16x8 o;
    o[0]=(__bf16)v0.x; o[1]=(__bf16)v0.y; o[2]=(__bf16)v0.z; o[3]=(__bf16)v0.w;
    o[4]=(__bf16)v1.x; o[5]=(__bf16)v1.y; o[6]=(__bf16)v1.z; o[7]=(__bf16)v1.w;
    *(bf16x8*)(ws + (size_t)g * 8) = o;
}

// Fused expert MLP. Block = (b, e, 128-l tile), 16 waves.
// Wave (lt = w>>1, role = w&1): GEMM1 f-half(role) for its 16-l; GEMM2 c-half(role).
__global__ __launch_bounds__(1024, 4)
void experts_kernel(const float* __restrict__ x,
                    const __bf16* __restrict__ w1ws,
                    const float* __restrict__ b1,
                    const __bf16* __restrict__ w2ws,
                    const float* __restrict__ b2,
                    float* __restrict__ out)
{
    __shared__ __align__(16) __bf16 sW1[3][FC * CC];      // 48 KB, [cgran32][f32][8]
    __shared__ __align__(16) __bf16 sW2[3][CC * FC];      // 48 KB, [fgran4][c256][8]
    __shared__ __align__(16) __bf16 sH[2][8][16 * HSTR];  // 28 KB

    const int tid  = threadIdx.x;
    const int lane = tid & 63;
    const int w    = tid >> 6;          // 0..15
    const int l15  = lane & 15, q4 = lane >> 4;
    const int lt   = w >> 1;            // l-tile 0..7
    const int fh   = w & 1;             // f-half (GEMM1) / c-half (GEMM2)

    const int bid  = blockIdx.x;
    const int e    = ((bid & 7) << 1) | ((bid >> 3) & 1);  // 2 experts per XCD
    const int rest = bid >> 4;
    const int bb   = rest & 7;
    const int l0   = (rest >> 3) * TL;
    const int lb   = l0 + 16 * lt;

    const __bf16* w1c = w1ws + (size_t)e * NCH * (FC * CC);
    const __bf16* w2c = w2ws + (size_t)e * NCH * (CC * FC);
    const int slice = w * 512;  // 1 KB per wave

    // prologue: stage chunks 0,1
    gld_lds16(w1c + 0 * 8192 + slice + lane * 8, &sW1[0][slice]);
    gld_lds16(w2c + 0 * 8192 + slice + lane * 8, &sW2[0][slice]);
    gld_lds16(w1c + 1 * 8192 + slice + lane * 8, &sW1[1][slice]);
    gld_lds16(w2c + 1 * 8192 + slice + lane * 8, &sW2[1][slice]);

    // x fragments: B-layout, n=l15, k(c) = 32*ks + 8*q4 + t   (32 VGPRs)
    bf16x8 xf[8];
    {
        const float* xp = x + ((size_t)(bb * EE + e) * CC) * LL + lb + l15;
        #pragma unroll
        for (int ks = 0; ks < 8; ++ks) {
            bf16x8 f;
            #pragma unroll
            for (int t = 0; t < 8; ++t)
                f[t] = (__bf16)xp[(size_t)(32 * ks + 8 * q4 + t) * LL];
            xf[ks] = f;
        }
    }

    // y accum: c-half (128) x 16 l = 8 tiles x 4 = 32 regs
    f32x4 accY[8];
    #pragma unroll
    for (int t = 0; t < 8; ++t) accY[t] = f32x4{0.f, 0.f, 0.f, 0.f};

    __syncthreads();  // drains prologue DMA

    int cur = 0;
    #pragma unroll 1
    for (int ch = 0; ch < NCH; ++ch) {
        const int p = ch & 1;

        // ---- GEMM1: h[f-half, my 16 l] over K=C=256 ----
        const float4 bv = *(const float4*)(b1 + e * FF + ch * FC + 16 * fh + 4 * q4);
        f32x4 acc1 = f32x4{0.f, 0.f, 0.f, 0.f};
        const __bf16* a1base = &sW1[cur][(16 * fh + l15) * 8];
        #pragma unroll
        for (int ks = 0; ks < 8; ++ks) {
            // [cgran = 4ks+q4][f = 16fh+l15][8]
            bf16x8 a = *(const bf16x8*)(a1base + (4 * ks + q4) * 256);
            acc1 = mfma16(a, xf[ks], acc1);
        }
        // bias + SiLU -> h (wave-pair LDS, [l][f] rows)
        {
            bf16x4 hv;
            #pragma unroll
            for (int r = 0; r < 4; ++r) {
                float v = acc1[r] + ((const float*)&bv)[r];
                hv[r] = (__bf16)(v / (1.0f + __expf(-v)));
            }
            *(bf16x4*)(&sH[p][lt][l15 * HSTR + 16 * fh + 4 * q4]) = hv;
        }

        __syncthreads();  // the ONE barrier: h visible + chunk ch+1 DMA drained (from prev iter)

        // ---- stage chunk ch+2 (distance-2; consumed after NEXT barrier) ----
        if (ch + 2 < NCH) {
            int nxt = cur + 2; if (nxt >= 3) nxt -= 3;
            gld_lds16(w1c + (size_t)(ch + 2) * 8192 + slice + lane * 8, &sW1[nxt][slice]);
            gld_lds16(w2c + (size_t)(ch + 2) * 8192 + slice + lane * 8, &sW2[nxt][slice]);
        }

        // ---- GEMM2: y[c-half, my 16 l] += W2[c, f-chunk] @ h ----
        {
            bf16x8 hf = *(const bf16x8*)(&sH[p][lt][l15 * HSTR + 8 * q4]);
            const __bf16* a2base = &sW2[cur][(128 * fh + l15) * 8];
            #pragma unroll
            for (int t = 0; t < 8; ++t) {
                // [fgran = q4][c = 128fh+16t+l15][8]
                bf16x8 a = *(const bf16x8*)(a2base + (q4 * 256 + 16 * t) * 8);
                accY[t] = mfma16(a, hf, accY[t]);
            }
        }
        ++cur; if (cur == 3) cur = 0;
    }

    // ---- epilogue: + b2, fp32 stores (16-lane 64B segments) ----
    float* outp = out + ((size_t)(bb * EE + e) * CC) * LL + lb + l15;
    #pragma unroll
    for (int t = 0; t < 8; ++t) {
        const int c0 = 128 * fh + 16 * t + 4 * q4;
        const float4 b2v = *(const float4*)(b2 + e * CC + c0);
        #pragma unroll
        for (int r = 0; r < 4; ++r) {
            __builtin_nontemporal_store(accY[t][r] + ((const float*)&b2v)[r],
                                        outp + (size_t)(c0 + r) * LL);
        }
    }
}

extern "C" void kernel_launch(void* const* d_in, const int* in_sizes, int n_in,
                              void* d_out, int out_size, void* d_ws, size_t ws_size,
                              hipStream_t stream)
{
    const float* x  = (const float*)d_in[0];
    const float* W1 = (const float*)d_in[1];
    const float* b1 = (const float*)d_in[2];
    const float* W2 = (const float*)d_in[3];
    const float* b2 = (const float*)d_in[4];
    float* out = (float*)d_out;

    const size_t nW1 = (size_t)EE * FF * CC;   // 4194304 elems
    const size_t nW2 = (size_t)EE * CC * FF;
    __bf16* w1bf = (__bf16*)d_ws;              // 8.39 MB
    __bf16* w2bf = w1bf + nW1;                 // + 8.39 MB  (ws_size >= 16.8 MB, verified R1)

    const int ng = (int)(nW1 / 8);             // 524288 granules each
    cvt_w1<<<dim3(ng / 256), dim3(256), 0, stream>>>(W1, w1bf);
    cvt_w2<<<dim3(ng / 256), dim3(256), 0, stream>>>(W2, w2bf);

    experts_kernel<<<dim3(BB * EE * (LL / TL)), dim3(1024), 0, stream>>>(
        x, w1bf, b1, w2bf, b2, out);
}